// Round 9
// baseline (3499.494 us; speedup 1.0000x reference)
//
#include <hip/hip_runtime.h>
#include <math.h>

#define B_   16
#define N_   2048
#define S_   1025
#define K_   16
#define EMB_ 64
#define NF_  (B_ * S_ * K_)   // 262400
#define NCH_ (NF_ / 64)       // 4100 column-chunks of 64

typedef float v2f __attribute__((ext_vector_type(2)));

// ---------------- FPS: ONE WAVE per batch, fp32 bit-exact, packed-key argmax --------------
// Distance math: validated pk-asm sequence (rn(rn(dx*dx)+rn(dy*dy)), dx=rn(px+(-cx))),
// running fminf == jnp.minimum. Argmax via 64-bit key (bits(dist)<<32)|~idx: dist>=0 so the
// float bit pattern is unsigned-monotone; ~idx makes ties pick the LOWEST index == np.argmax.
// Per-lane candidate (val,idx,x,y) tracked in 4 parallel chains (strict >, ascending j ==
// first-occurrence ties); winner's coords fetched by readlane(cand, cur>>5) -- no LDS at all.
__global__ __launch_bounds__(64) __attribute__((amdgpu_waves_per_eu(1, 1)))
void fps_kernel(const float* __restrict__ xy,
                int* __restrict__ fps_idx,
                float* __restrict__ new_xyz,
                float* __restrict__ out0) {
  const int b = blockIdx.x;
  const int lane = threadIdx.x;   // 0..63
  const float* xb = xy + (size_t)b * 2 * N_;
  const float2* xb2 = (const float2*)xb;
  const float2* yb2 = (const float2*)(xb + N_);
  v2f pxp[16], pyp[16];
  float dist[32];
#pragma unroll
  for (int q = 0; q < 16; ++q) {
    float2 x01 = xb2[lane * 16 + q];
    float2 y01 = yb2[lane * 16 + q];
    pxp[q][0] = x01.x; pxp[q][1] = x01.y;
    pyp[q][0] = y01.x; pyp[q][1] = y01.y;
    dist[2 * q] = __builtin_inff();
    dist[2 * q + 1] = __builtin_inff();
  }
#pragma unroll
  for (int q = 0; q < 16; ++q) {   // opaque pin: forces true VGPR residency
    asm volatile("" : "+v"(pxp[q]), "+v"(pyp[q]));
  }
  int cur = 0;
  float cx = xb[0], cy = xb[N_];   // coords of point 0 (uniform load, one-time)
  for (int t = 0; t < S_; ++t) {
    if (lane == 0) {
      fps_idx[b * S_ + t] = cur;
      new_xyz[(b * S_ + t) * 2 + 0] = cx;
      new_xyz[(b * S_ + t) * 2 + 1] = cy;
      out0[b * 2 * S_ + t] = cx;
      out0[b * 2 * S_ + S_ + t] = cy;
    }
    v2f ncx2; ncx2[0] = -cx; ncx2[1] = -cx;   // negation exact; pk_add(x,-c) == rn(x-c)
    v2f ncy2; ncy2[0] = -cy; ncy2[1] = -cy;
    float gm[4]; int gi[4]; float gx[4], gy[4];
#pragma unroll
    for (int g = 0; g < 4; ++g) { gm[g] = -__builtin_inff(); gi[g] = 0; gx[g] = 0.f; gy[g] = 0.f; }
#pragma unroll
    for (int q = 0; q < 16; ++q) {
      v2f dx, dy, sx, sy, dd;
      asm("v_pk_add_f32 %0, %1, %2" : "=v"(dx) : "v"(pxp[q]), "v"(ncx2));
      asm("v_pk_add_f32 %0, %1, %2" : "=v"(dy) : "v"(pyp[q]), "v"(ncy2));
      asm("v_pk_mul_f32 %0, %1, %1" : "=v"(sx) : "v"(dx));
      asm("v_pk_mul_f32 %0, %1, %1" : "=v"(sy) : "v"(dy));
      asm("v_pk_add_f32 %0, %1, %2" : "=v"(dd) : "v"(sx), "v"(sy));
      const int g = q >> 2;
      float nd0 = fminf(dist[2 * q], dd[0]);
      float nd1 = fminf(dist[2 * q + 1], dd[1]);
      dist[2 * q] = nd0;
      dist[2 * q + 1] = nd1;
      if (nd0 > gm[g]) { gm[g] = nd0; gi[g] = 2 * q;     gx[g] = pxp[q][0]; gy[g] = pyp[q][0]; }
      if (nd1 > gm[g]) { gm[g] = nd1; gi[g] = 2 * q + 1; gx[g] = pxp[q][1]; gy[g] = pyp[q][1]; }
    }
    // left-preferring tree merge (ties keep lower group -> lower index)
    float m0 = gm[0], x0 = gx[0], y0 = gy[0]; int i0 = gi[0];
    if (gm[1] > m0) { m0 = gm[1]; i0 = gi[1]; x0 = gx[1]; y0 = gy[1]; }
    float m2 = gm[2], x2 = gx[2], y2 = gy[2]; int i2 = gi[2];
    if (gm[3] > m2) { m2 = gm[3]; i2 = gi[3]; x2 = gx[3]; y2 = gy[3]; }
    if (m2 > m0) { m0 = m2; i0 = i2; x0 = x2; y0 = y2; }
    // 64-bit packed key: (bits(val)<<32) | ~(global idx)
    int lo_i = (int)~(unsigned)(lane * 32 + i0);
    int hi_i = __float_as_int(m0);
#define DPP64_MAX(CTRL)                                                               \
    {                                                                                 \
      int tl = __builtin_amdgcn_update_dpp(lo_i, lo_i, (CTRL), 0xF, 0xF, false);      \
      int th = __builtin_amdgcn_update_dpp(hi_i, hi_i, (CTRL), 0xF, 0xF, false);      \
      unsigned long long a = ((unsigned long long)(unsigned)hi_i << 32) | (unsigned)lo_i; \
      unsigned long long bq = ((unsigned long long)(unsigned)th << 32) | (unsigned)tl;    \
      if (bq > a) { hi_i = th; lo_i = tl; }                                           \
    }
    DPP64_MAX(0x111)  // row_shr:1
    DPP64_MAX(0x112)  // row_shr:2
    DPP64_MAX(0x114)  // row_shr:4
    DPP64_MAX(0x118)  // row_shr:8
    DPP64_MAX(0x142)  // row_bcast:15
    DPP64_MAX(0x143)  // row_bcast:31 -> lane63 = global max key
#undef DPP64_MAX
    const unsigned glo = (unsigned)__builtin_amdgcn_readlane(lo_i, 63);
    cur = (int)~glo;                       // global argmax index (lowest-index ties)
    const int wl = cur >> 5;               // owning lane (contiguous ownership)
    cx = __int_as_float(__builtin_amdgcn_readlane(__float_as_int(x0), wl));
    cy = __int_as_float(__builtin_amdgcn_readlane(__float_as_int(y0), wl));
  }
}

// ---------------- KNN fp64-exact, 16 lanes per query point (validated) ----------------
__global__ __launch_bounds__(256) void knn_kernel(const float* __restrict__ xy,
                                                  const int* __restrict__ fps_idx,
                                                  int* __restrict__ knn_sel) {
  const int b = blockIdx.y;
  __shared__ float2 lxy[N_];    // 16 KB
  __shared__ double lsq[N_];    // 16 KB
  const float* xb = xy + (size_t)b * 2 * N_;
  for (int p = threadIdx.x; p < N_; p += 256) {
    float x = xb[p], y = xb[N_ + p];
    lxy[p] = make_float2(x, y);
    lsq[p] = (double)x * (double)x + (double)y * (double)y;  // exact
  }
  __syncthreads();
  const int t = threadIdx.x;
  const int s = blockIdx.x * 16 + (t >> 4);
  if (s >= S_) return;
  const int oct = t & 15;
  const int p0 = fps_idx[b * S_ + s];
  float2 q = lxy[p0];
  const double xn = (double)q.x, yn = (double)q.y;
  const double sqn = lsq[p0];
  double d16[16];
  int i16[16];
#pragma unroll
  for (int j = 0; j < 16; ++j) { d16[j] = __builtin_inf(); i16[j] = 0x7fffffff; }
  const int mlo = oct * 128;
  for (int m0 = mlo; m0 < mlo + 128; m0 += 4) {
    double dd[4];
#pragma unroll
    for (int u = 0; u < 4; ++u) {
      float2 p = lxy[m0 + u];
      double dot = (double)p.x * xn + (double)p.y * yn;
      dd[u] = (sqn - 2.0 * dot) + lsq[m0 + u];
    }
#pragma unroll
    for (int u = 0; u < 4; ++u) {
      if (dd[u] < d16[15]) {
        double d = dd[u];
        int mi = m0 + u;
#pragma unroll
        for (int j = 15; j >= 1; --j) {
          bool shift = d < d16[j - 1];
          bool ins = d < d16[j];
          d16[j] = shift ? d16[j - 1] : (ins ? d : d16[j]);
          i16[j] = shift ? i16[j - 1] : (ins ? mi : i16[j]);
        }
        if (d < d16[0]) { d16[0] = d; i16[0] = mi; }
      }
    }
  }
#pragma unroll
  for (int w = 1; w <= 8; w <<= 1) {
    double nd[16]; int ni[16];
#pragma unroll
    for (int i = 0; i < 16; ++i) {
      double rd = __shfl_xor(d16[15 - i], w, 64);
      int ri = __shfl_xor(i16[15 - i], w, 64);
      bool takeR = (rd < d16[i]) || (rd == d16[i] && ri < i16[i]);
      nd[i] = takeR ? rd : d16[i];
      ni[i] = takeR ? ri : i16[i];
    }
#pragma unroll
    for (int i = 0; i < 16; ++i) { d16[i] = nd[i]; i16[i] = ni[i]; }
    if (w < 8) {
#pragma unroll
      for (int dstg = 8; dstg >= 1; dstg >>= 1) {
#pragma unroll
        for (int i = 0; i < 16; ++i) {
          if ((i & dstg) == 0) {
            int a = i, c = i + dstg;
            bool sw = (d16[a] > d16[c]) || (d16[a] == d16[c] && i16[a] > i16[c]);
            double tlo = sw ? d16[c] : d16[a];
            double thi = sw ? d16[a] : d16[c];
            int ulo = sw ? i16[c] : i16[a];
            int uhi = sw ? i16[a] : i16[c];
            d16[a] = tlo; d16[c] = thi; i16[a] = ulo; i16[c] = uhi;
          }
        }
      }
    }
  }
  if (oct == 0) {
    int* dst = knn_sel + ((size_t)b * S_ + s) * K_;
#pragma unroll
    for (int j = 0; j < 16; ++j) dst[j] = i16[j];
  }
}

// ---------------- P[b][pt][c] = sum_e W1[c][2+e] * fea[b][e][pt] ----------------
__global__ __launch_bounds__(256) void pk_kernel(const float* __restrict__ fea,
                                                 const float* __restrict__ W1,
                                                 float* __restrict__ P) {
  const int t = threadIdx.x;
  const int b = blockIdx.x >> 5;
  const int pt0 = (blockIdx.x & 31) << 6;
  __shared__ float W1L[64 * 64];   // [e][c]
  __shared__ float feaL[64 * 64];  // [e][pt]
#pragma unroll
  for (int p = 0; p < 16; ++p) {
    int idx = t + 256 * p;
    int c = idx >> 6, e = idx & 63;
    W1L[e * 64 + c] = W1[c * 66 + 2 + e];
    int r = (t >> 6) + 4 * p, cc = t & 63;
    feaL[r * 64 + cc] = fea[((size_t)b * 64 + r) * N_ + pt0 + cc];
  }
  __syncthreads();
  const int tpt = t & 15, tcq = t >> 4;
  float acc[4][4];
#pragma unroll
  for (int i = 0; i < 4; ++i)
#pragma unroll
    for (int j = 0; j < 4; ++j) acc[i][j] = 0.f;
  for (int e = 0; e < 64; ++e) {
    float4 a4 = *reinterpret_cast<const float4*>(&W1L[e * 64 + tcq * 4]);
    float4 b4 = *reinterpret_cast<const float4*>(&feaL[e * 64 + tpt * 4]);
    const float av[4] = {a4.x, a4.y, a4.z, a4.w};
    const float bvv[4] = {b4.x, b4.y, b4.z, b4.w};
#pragma unroll
    for (int i = 0; i < 4; ++i)
#pragma unroll
      for (int j = 0; j < 4; ++j) acc[i][j] = fmaf(av[i], bvv[j], acc[i][j]);
  }
#pragma unroll
  for (int j = 0; j < 4; ++j) {
    int pt = tpt * 4 + j;
    float4 v = {acc[0][j], acc[1][j], acc[2][j], acc[3][j]};
    *reinterpret_cast<float4*>(&P[((size_t)(b * N_ + pt0 + pt)) * 64 + tcq * 4]) = v;
  }
}

// ---------------- Y1[64][NF]: gather P + W1a*dxy + b1 ----------------
__global__ __launch_bounds__(256) void yk1_kernel(const float* __restrict__ xy,
                                                  const int* __restrict__ knn_sel,
                                                  const float* __restrict__ new_xyz,
                                                  const float* __restrict__ P,
                                                  const float* __restrict__ W1,
                                                  const float* __restrict__ b1,
                                                  float* __restrict__ Y1) {
  __shared__ float w0s[64], w1s[64], bbs[64];
  const int t = threadIdx.x;
  if (t < 64) { w0s[t] = W1[t * 66 + 0]; w1s[t] = W1[t * 66 + 1]; bbs[t] = b1[t]; }
  __syncthreads();
  const int n = blockIdx.x * 256 + t;
  const int bs = n >> 4;
  const int b = bs / S_;
  const int nbr = knn_sel[n];
  const float dx = xy[(size_t)b * 2 * N_ + nbr] - new_xyz[bs * 2 + 0];
  const float dy = xy[(size_t)b * 2 * N_ + N_ + nbr] - new_xyz[bs * 2 + 1];
  const float* prow = &P[((size_t)(b * N_ + nbr)) * 64];
  for (int c4 = 0; c4 < 64; c4 += 4) {
    float4 p4 = *reinterpret_cast<const float4*>(&prow[c4]);
    float v0 = p4.x + w0s[c4 + 0] * dx + w1s[c4 + 0] * dy + bbs[c4 + 0];
    float v1 = p4.y + w0s[c4 + 1] * dx + w1s[c4 + 1] * dy + bbs[c4 + 1];
    float v2 = p4.z + w0s[c4 + 2] * dx + w1s[c4 + 2] * dy + bbs[c4 + 2];
    float v3 = p4.w + w0s[c4 + 3] * dx + w1s[c4 + 3] * dy + bbs[c4 + 3];
    Y1[(size_t)(c4 + 0) * NF_ + n] = v0;
    Y1[(size_t)(c4 + 1) * NF_ + n] = v1;
    Y1[(size_t)(c4 + 2) * NF_ + n] = v2;
    Y1[(size_t)(c4 + 3) * NF_ + n] = v3;
  }
}

// ---------------- per-row sum + sumsq in one pass (fp64) ----------------
__global__ __launch_bounds__(1024) void rowstats_kernel(const float* __restrict__ Y,
                                                        double* __restrict__ sum_out,
                                                        double* __restrict__ sq_out) {
  const int r = blockIdx.x;
  const float* row = Y + (size_t)r * NF_;
  double s = 0.0, s2 = 0.0;
  for (int i = threadIdx.x * 4; i < NF_; i += 4096) {
    float4 v = *reinterpret_cast<const float4*>(&row[i]);
    double dx = v.x, dy = v.y, dz = v.z, dw = v.w;
    s += (dx + dy) + (dz + dw);
    s2 = fma(dx, dx, s2); s2 = fma(dy, dy, s2);
    s2 = fma(dz, dz, s2); s2 = fma(dw, dw, s2);
  }
  __shared__ double sh[1024], sh2[1024];
  sh[threadIdx.x] = s; sh2[threadIdx.x] = s2;
  __syncthreads();
  for (int o = 512; o > 0; o >>= 1) {
    if (threadIdx.x < o) {
      sh[threadIdx.x] += sh[threadIdx.x + o];
      sh2[threadIdx.x] += sh2[threadIdx.x + o];
    }
    __syncthreads();
  }
  if (threadIdx.x == 0) { sum_out[r] = sh[0]; sq_out[r] = sh2[0]; }
}

// ---------------- A = g*rsqrt(var+eps); D = be - A*mu (sum/sumsq form, validated) ----------
__global__ void absch_kernel(const double* __restrict__ sumv, const double* __restrict__ sqv,
                             const float* __restrict__ g, const float* __restrict__ be,
                             float* __restrict__ A, float* __restrict__ D, int M) {
  int m = threadIdx.x;
  if (m >= M) return;
  double mu = sumv[m] * (1.0 / NF_);
  double var = sqv[m] * (1.0 / NF_) - mu * mu;
  double a = (double)g[m] / sqrt(var + 1e-5);
  A[m] = (float)a;
  D[m] = (float)((double)be[m] - a * mu);
}

// ---------------- reduce partials [P][2M] -> sum[M], sq[M] (fp64) ----------------
__global__ void redab_kernel(const float* __restrict__ parts, double* __restrict__ sum_out,
                             double* __restrict__ sq_out, int P, int M) {
  int m = threadIdx.x;
  if (m >= M) return;
  double a = 0.0, b = 0.0;
  for (int p = 0; p < P; ++p) {
    a += (double)parts[(size_t)p * 2 * M + m];
    b += (double)parts[(size_t)p * 2 * M + M + m];
  }
  sum_out[m] = a;
  sq_out[m] = b;
}

// ============ passA: GEMM2 per chunk, accumulate sum(y2), sum(y2^2) ============
__global__ __launch_bounds__(256) void passA_kernel(const float* __restrict__ Y1,
                                                    const float* __restrict__ W2,
                                                    const float* __restrict__ A1v,
                                                    const float* __restrict__ Bc1v,
                                                    float* __restrict__ parts) {
  __shared__ float W2L[64 * 128];
  __shared__ float ab[128];
  __shared__ float vpart[16][128];
  const int t = threadIdx.x;
#pragma unroll
  for (int p = 0; p < 32; ++p) {
    int idx = t + 256 * p;
    int m = idx >> 6, k = idx & 63;
    W2L[k * 128 + m] = W2[m * 64 + k];
  }
  if (t < 64) { ab[t] = A1v[t]; ab[64 + t] = Bc1v[t]; }
  const int tmA = t >> 4, tcA = t & 15;
  float vs[8], vq[8];
#pragma unroll
  for (int i = 0; i < 8; ++i) { vs[i] = 0.f; vq[i] = 0.f; }
  __syncthreads();
  for (int ch = blockIdx.x; ch < NCH_; ch += 512) {
    const size_t n0 = (size_t)ch * 64;
    float acc[8][4];
#pragma unroll
    for (int i = 0; i < 8; ++i)
#pragma unroll
      for (int j = 0; j < 4; ++j) acc[i][j] = 0.f;
#pragma unroll 2
    for (int k = 0; k < 64; ++k) {
      float4 y4 = *reinterpret_cast<const float4*>(&Y1[(size_t)k * NF_ + n0 + tcA * 4]);
      float a1 = ab[k], c1 = ab[64 + k];
      float bx[4];
      bx[0] = fmaxf(fmaf(y4.x, a1, c1), 0.f);
      bx[1] = fmaxf(fmaf(y4.y, a1, c1), 0.f);
      bx[2] = fmaxf(fmaf(y4.z, a1, c1), 0.f);
      bx[3] = fmaxf(fmaf(y4.w, a1, c1), 0.f);
      const float4* ap = reinterpret_cast<const float4*>(&W2L[k * 128 + tmA * 8]);
      float4 a0 = ap[0], a4 = ap[1];
      const float av[8] = {a0.x, a0.y, a0.z, a0.w, a4.x, a4.y, a4.z, a4.w};
#pragma unroll
      for (int i = 0; i < 8; ++i)
#pragma unroll
        for (int j = 0; j < 4; ++j) acc[i][j] = fmaf(av[i], bx[j], acc[i][j]);
    }
#pragma unroll
    for (int i = 0; i < 8; ++i)
#pragma unroll
      for (int j = 0; j < 4; ++j) {
        float y = acc[i][j];
        vs[i] += y;
        vq[i] = fmaf(y, y, vq[i]);
      }
  }
#pragma unroll
  for (int i = 0; i < 8; ++i) vpart[tcA][tmA * 8 + i] = vs[i];
  __syncthreads();
  if (t < 128) {
    float s = 0.f;
    for (int q = 0; q < 16; ++q) s += vpart[q][t];
    parts[(size_t)blockIdx.x * 256 + t] = s;
  }
  __syncthreads();
#pragma unroll
  for (int i = 0; i < 8; ++i) vpart[tcA][tmA * 8 + i] = vq[i];
  __syncthreads();
  if (t < 128) {
    float s = 0.f;
    for (int q = 0; q < 16; ++q) s += vpart[q][t];
    parts[(size_t)blockIdx.x * 256 + 128 + t] = s;
  }
}

// ============ passB: GEMM2 -> x2 -> GEMM3 per chunk, accumulate sum(y3), sum(y3^2) ============
__global__ __launch_bounds__(256) void passB_kernel(const float* __restrict__ Y1,
                                                    const float* __restrict__ W2,
                                                    const float* __restrict__ W3,
                                                    const float* __restrict__ A1v,
                                                    const float* __restrict__ Bc1v,
                                                    const float* __restrict__ A2v,
                                                    const float* __restrict__ D2v,
                                                    float* __restrict__ parts) {
  __shared__ float W2L[64 * 128];
  __shared__ float ab[128];
  __shared__ float X2s[128 * 68];
  __shared__ float W3c[16 * 256];
  __shared__ float vpart3[8][256];
  const int t = threadIdx.x;
#pragma unroll
  for (int p = 0; p < 32; ++p) {
    int idx = t + 256 * p;
    int m = idx >> 6, k = idx & 63;
    W2L[k * 128 + m] = W2[m * 64 + k];
  }
  if (t < 64) { ab[t] = A1v[t]; ab[64 + t] = Bc1v[t]; }
  const int tmA = t >> 4, tcA = t & 15;
  const int tm3 = t & 31, tcol = t >> 5;
  float a2r[8], d2r[8], vs[8], vq[8];
#pragma unroll
  for (int i = 0; i < 8; ++i) {
    a2r[i] = A2v[tmA * 8 + i];
    d2r[i] = D2v[tmA * 8 + i];
    vs[i] = 0.f; vq[i] = 0.f;
  }
  __syncthreads();
  for (int ch = blockIdx.x; ch < NCH_; ch += 256) {
    const size_t n0 = (size_t)ch * 64;
    {
      float acc[8][4];
#pragma unroll
      for (int i = 0; i < 8; ++i)
#pragma unroll
        for (int j = 0; j < 4; ++j) acc[i][j] = 0.f;
#pragma unroll 2
      for (int k = 0; k < 64; ++k) {
        float4 y4 = *reinterpret_cast<const float4*>(&Y1[(size_t)k * NF_ + n0 + tcA * 4]);
        float a1 = ab[k], c1 = ab[64 + k];
        float bx[4];
        bx[0] = fmaxf(fmaf(y4.x, a1, c1), 0.f);
        bx[1] = fmaxf(fmaf(y4.y, a1, c1), 0.f);
        bx[2] = fmaxf(fmaf(y4.z, a1, c1), 0.f);
        bx[3] = fmaxf(fmaf(y4.w, a1, c1), 0.f);
        const float4* ap = reinterpret_cast<const float4*>(&W2L[k * 128 + tmA * 8]);
        float4 a0 = ap[0], a4 = ap[1];
        const float av[8] = {a0.x, a0.y, a0.z, a0.w, a4.x, a4.y, a4.z, a4.w};
#pragma unroll
        for (int i = 0; i < 8; ++i)
#pragma unroll
          for (int j = 0; j < 4; ++j) acc[i][j] = fmaf(av[i], bx[j], acc[i][j]);
      }
#pragma unroll
      for (int i = 0; i < 8; ++i) {
        float4 v;
        v.x = fmaxf(fmaf(acc[i][0], a2r[i], d2r[i]), 0.f);
        v.y = fmaxf(fmaf(acc[i][1], a2r[i], d2r[i]), 0.f);
        v.z = fmaxf(fmaf(acc[i][2], a2r[i], d2r[i]), 0.f);
        v.w = fmaxf(fmaf(acc[i][3], a2r[i], d2r[i]), 0.f);
        *reinterpret_cast<float4*>(&X2s[(tmA * 8 + i) * 68 + tcA * 4]) = v;
      }
    }
    __syncthreads();
    float acc3[8][8];
#pragma unroll
    for (int i = 0; i < 8; ++i)
#pragma unroll
      for (int j = 0; j < 8; ++j) acc3[i][j] = 0.f;
    for (int kc = 0; kc < 8; ++kc) {
#pragma unroll
      for (int q = 0; q < 4; ++q) {
        float4 w = *reinterpret_cast<const float4*>(&W3[(size_t)t * 128 + kc * 16 + q * 4]);
        W3c[(q * 4 + 0) * 256 + t] = w.x;
        W3c[(q * 4 + 1) * 256 + t] = w.y;
        W3c[(q * 4 + 2) * 256 + t] = w.z;
        W3c[(q * 4 + 3) * 256 + t] = w.w;
      }
      __syncthreads();
#pragma unroll
      for (int kk = 0; kk < 16; ++kk) {
        const float4* ap = reinterpret_cast<const float4*>(&W3c[kk * 256 + tm3 * 8]);
        float4 a0 = ap[0], a4 = ap[1];
        const float4* bp = reinterpret_cast<const float4*>(&X2s[(kc * 16 + kk) * 68 + tcol * 8]);
        float4 b0 = bp[0], b4 = bp[1];
        const float av[8] = {a0.x, a0.y, a0.z, a0.w, a4.x, a4.y, a4.z, a4.w};
        const float bw[8] = {b0.x, b0.y, b0.z, b0.w, b4.x, b4.y, b4.z, b4.w};
#pragma unroll
        for (int i = 0; i < 8; ++i)
#pragma unroll
          for (int j = 0; j < 8; ++j) acc3[i][j] = fmaf(av[i], bw[j], acc3[i][j]);
      }
      __syncthreads();
    }
#pragma unroll
    for (int i = 0; i < 8; ++i)
#pragma unroll
      for (int j = 0; j < 8; ++j) {
        float y = acc3[i][j];
        vs[i] += y;
        vq[i] = fmaf(y, y, vq[i]);
      }
    __syncthreads();
  }
#pragma unroll
  for (int i = 0; i < 8; ++i) vpart3[tcol][tm3 * 8 + i] = vs[i];
  __syncthreads();
  {
    float s = 0.f;
    for (int q = 0; q < 8; ++q) s += vpart3[q][t];
    parts[(size_t)blockIdx.x * 512 + t] = s;
  }
  __syncthreads();
#pragma unroll
  for (int i = 0; i < 8; ++i) vpart3[tcol][tm3 * 8 + i] = vq[i];
  __syncthreads();
  {
    float s = 0.f;
    for (int q = 0; q < 8; ++q) s += vpart3[q][t];
    parts[(size_t)blockIdx.x * 512 + 256 + t] = s;
  }
}

// ============ final pass: GEMM2 -> BN -> relu -> GEMM3 -> BN -> max over k -> relu ============
__global__ __launch_bounds__(256) void final_kernel(const float* __restrict__ Y1,
                                                    const float* __restrict__ W2,
                                                    const float* __restrict__ W3,
                                                    const float* __restrict__ A1v,
                                                    const float* __restrict__ Bc1v,
                                                    const float* __restrict__ A2v,
                                                    const float* __restrict__ D2v,
                                                    const float* __restrict__ A3v,
                                                    const float* __restrict__ D3v,
                                                    float* __restrict__ out1) {
  __shared__ float W2L[64 * 128];   // aliased as W3c in phase B
  __shared__ float ab[128];
  __shared__ float X2s[128 * 68];
  float* W3c = W2L;
  const int t = threadIdx.x;
#pragma unroll
  for (int p = 0; p < 32; ++p) {
    int idx = t + 256 * p;
    int m = idx >> 6, k = idx & 63;
    W2L[k * 128 + m] = W2[m * 64 + k];
  }
  if (t < 64) { ab[t] = A1v[t]; ab[64 + t] = Bc1v[t]; }
  const int tmA = t >> 4, tcA = t & 15;
  const int tm3 = t & 31, tcol = t >> 5;
  float a2r[8], d2r[8], a3r[8], d3r[8];
#pragma unroll
  for (int i = 0; i < 8; ++i) {
    a2r[i] = A2v[tmA * 8 + i];
    d2r[i] = D2v[tmA * 8 + i];
    a3r[i] = A3v[tm3 * 8 + i];
    d3r[i] = D3v[tm3 * 8 + i];
  }
  __syncthreads();
  const int ch = blockIdx.x;
  const size_t n0 = (size_t)ch * 64;
  {
    float acc[8][4];
#pragma unroll
    for (int i = 0; i < 8; ++i)
#pragma unroll
      for (int j = 0; j < 4; ++j) acc[i][j] = 0.f;
#pragma unroll 2
    for (int k = 0; k < 64; ++k) {
      float4 y4 = *reinterpret_cast<const float4*>(&Y1[(size_t)k * NF_ + n0 + tcA * 4]);
      float a1 = ab[k], c1 = ab[64 + k];
      float bx[4];
      bx[0] = fmaxf(fmaf(y4.x, a1, c1), 0.f);
      bx[1] = fmaxf(fmaf(y4.y, a1, c1), 0.f);
      bx[2] = fmaxf(fmaf(y4.z, a1, c1), 0.f);
      bx[3] = fmaxf(fmaf(y4.w, a1, c1), 0.f);
      const float4* ap = reinterpret_cast<const float4*>(&W2L[k * 128 + tmA * 8]);
      float4 a0 = ap[0], a4 = ap[1];
      const float av[8] = {a0.x, a0.y, a0.z, a0.w, a4.x, a4.y, a4.z, a4.w};
#pragma unroll
      for (int i = 0; i < 8; ++i)
#pragma unroll
        for (int j = 0; j < 4; ++j) acc[i][j] = fmaf(av[i], bx[j], acc[i][j]);
    }
#pragma unroll
    for (int i = 0; i < 8; ++i) {
      float4 v;
      v.x = fmaxf(fmaf(acc[i][0], a2r[i], d2r[i]), 0.f);
      v.y = fmaxf(fmaf(acc[i][1], a2r[i], d2r[i]), 0.f);
      v.z = fmaxf(fmaf(acc[i][2], a2r[i], d2r[i]), 0.f);
      v.w = fmaxf(fmaf(acc[i][3], a2r[i], d2r[i]), 0.f);
      *reinterpret_cast<float4*>(&X2s[(tmA * 8 + i) * 68 + tcA * 4]) = v;
    }
  }
  __syncthreads();
  float acc3[8][8];
#pragma unroll
  for (int i = 0; i < 8; ++i)
#pragma unroll
    for (int j = 0; j < 8; ++j) acc3[i][j] = 0.f;
  for (int kc = 0; kc < 8; ++kc) {
#pragma unroll
    for (int q = 0; q < 4; ++q) {
      float4 w = *reinterpret_cast<const float4*>(&W3[(size_t)t * 128 + kc * 16 + q * 4]);
      W3c[(q * 4 + 0) * 256 + t] = w.x;
      W3c[(q * 4 + 1) * 256 + t] = w.y;
      W3c[(q * 4 + 2) * 256 + t] = w.z;
      W3c[(q * 4 + 3) * 256 + t] = w.w;
    }
    __syncthreads();
#pragma unroll
    for (int kk = 0; kk < 16; ++kk) {
      const float4* ap = reinterpret_cast<const float4*>(&W3c[kk * 256 + tm3 * 8]);
      float4 a0 = ap[0], a4 = ap[1];
      const float4* bp = reinterpret_cast<const float4*>(&X2s[(kc * 16 + kk) * 68 + tcol * 8]);
      float4 b0 = bp[0], b4 = bp[1];
      const float av[8] = {a0.x, a0.y, a0.z, a0.w, a4.x, a4.y, a4.z, a4.w};
      const float bw[8] = {b0.x, b0.y, b0.z, b0.w, b4.x, b4.y, b4.z, b4.w};
#pragma unroll
      for (int i = 0; i < 8; ++i)
#pragma unroll
        for (int j = 0; j < 8; ++j) acc3[i][j] = fmaf(av[i], bw[j], acc3[i][j]);
    }
    __syncthreads();
  }
#pragma unroll
  for (int i = 0; i < 8; ++i) {
    float mx = -__builtin_inff();
#pragma unroll
    for (int j = 0; j < 8; ++j) {
      float v = fmaf(acc3[i][j], a3r[i], d3r[i]);
      mx = fmaxf(mx, v);
    }
    float o = __shfl_xor(mx, 32, 64);
    mx = fmaxf(mx, o);
    if ((tcol & 1) == 0) {
      int g = tcol >> 1;
      int bs = ch * 4 + g;
      int b = bs / S_;
      int s = bs - b * S_;
      out1[((size_t)(b * 256 + tm3 * 8 + i)) * S_ + s] = fmaxf(mx, 0.f);
    }
  }
}

__global__ void diag_kernel(float* out, float v) {
  if (threadIdx.x == 0 && blockIdx.x == 0) out[0] = v;
}

extern "C" void kernel_launch(void* const* d_in, const int* in_sizes, int n_in,
                              void* d_out, int out_size, void* d_ws, size_t ws_size,
                              hipStream_t stream) {
  const float* xy  = (const float*)d_in[0];
  const float* fea = (const float*)d_in[1];
  const float* W1  = (const float*)d_in[2];
  const float* b1  = (const float*)d_in[3];
  const float* g1  = (const float*)d_in[4];
  const float* be1 = (const float*)d_in[5];
  const float* W2  = (const float*)d_in[6];
  const float* b2  = (const float*)d_in[7];
  const float* g2  = (const float*)d_in[8];
  const float* be2 = (const float*)d_in[9];
  const float* W3  = (const float*)d_in[10];
  const float* b3  = (const float*)d_in[11];
  const float* g3  = (const float*)d_in[12];
  const float* be3 = (const float*)d_in[13];
  (void)b2; (void)b3;
  float* out = (float*)d_out;
  float* out1 = out + B_ * 2 * S_;

  char* w = (char*)d_ws;
  size_t off = 0;
  auto take = [&](size_t bytes) -> void* {
    void* p = w + off;
    off += (bytes + 255) & ~(size_t)255;
    return p;
  };
  int*    fps_idx = (int*)take((size_t)B_ * S_ * 4);
  float*  new_xyz = (float*)take((size_t)B_ * S_ * 2 * 4);
  int*    knn_sel = (int*)take((size_t)NF_ * 4);
  float*  P       = (float*)take((size_t)B_ * N_ * 64 * 4);   // 8.4 MB
  float*  Y1      = (float*)take((size_t)64 * NF_ * 4);       // 67.2 MB
  double* Sy1     = (double*)take(64 * 8);
  double* Sq1     = (double*)take(64 * 8);
  float*  A1      = (float*)take(64 * 4);
  float*  Bc1     = (float*)take(64 * 4);
  float*  partsA  = (float*)take((size_t)512 * 256 * 4);
  double* Sy2     = (double*)take(128 * 8);
  double* Sq2     = (double*)take(128 * 8);
  float*  A2      = (float*)take(128 * 4);
  float*  D2      = (float*)take(128 * 4);
  float*  partsB  = (float*)take((size_t)256 * 512 * 4);
  double* Sy3     = (double*)take(256 * 8);
  double* Sq3     = (double*)take(256 * 8);
  float*  A3      = (float*)take(256 * 4);
  float*  D3      = (float*)take(256 * 4);

  if (off > ws_size) {
    diag_kernel<<<1, 64, 0, stream>>>(out, (float)(ws_size >> 20));
    return;
  }

  fps_kernel<<<B_, 64, 0, stream>>>(xy, fps_idx, new_xyz, out);
  knn_kernel<<<dim3((S_ + 15) / 16, B_), 256, 0, stream>>>(xy, fps_idx, knn_sel);
  pk_kernel<<<B_ * 32, 256, 0, stream>>>(fea, W1, P);
  yk1_kernel<<<NF_ / 256, 256, 0, stream>>>(xy, knn_sel, new_xyz, P, W1, b1, Y1);

  rowstats_kernel<<<64, 1024, 0, stream>>>(Y1, Sy1, Sq1);
  absch_kernel<<<1, 64, 0, stream>>>(Sy1, Sq1, g1, be1, A1, Bc1, 64);

  passA_kernel<<<512, 256, 0, stream>>>(Y1, W2, A1, Bc1, partsA);
  redab_kernel<<<1, 128, 0, stream>>>(partsA, Sy2, Sq2, 512, 128);
  absch_kernel<<<1, 128, 0, stream>>>(Sy2, Sq2, g2, be2, A2, D2, 128);

  passB_kernel<<<256, 256, 0, stream>>>(Y1, W2, W3, A1, Bc1, A2, D2, partsB);
  redab_kernel<<<1, 256, 0, stream>>>(partsB, Sy3, Sq3, 256, 256);
  absch_kernel<<<1, 256, 0, stream>>>(Sy3, Sq3, g3, be3, A3, D3, 256);

  final_kernel<<<NCH_, 256, 0, stream>>>(Y1, W2, W3, A1, Bc1, A2, D2, A3, D3, out1);
}